// Round 8
// baseline (210.374 us; speedup 1.0000x reference)
//
#include <hip/hip_runtime.h>
#include <math.h>

#define DIM 512
#define HH  1024
#define NB  64
#define NV  64
#define TBL_N 513           // nodes on [-8, 8], h = 1/32, node 256 at x=0

// ws layout (floats):
//   ctx   [64][1024]  @ 0        ((state+action)@Wx + b1)
//   cause [64][1024]  @ 65536    (embed@Wc)
//   effT  [1024][64]  @ 131072   (embed@We, TRANSPOSED: effT[h][j])
//   tblp  [513][2]    @ 196608   (gelu residual pairs (r_k, r_{k+1}))

// Build gelu-residual table with EXACT erf: r(x) = gelu(x) - max(x,0).
// r is bounded in [-0.17, 0] and -> 0 at both tails, so index clamping
// gives exact tails for |x| > 8.
extern "C" __global__ void cgl_table(float* __restrict__ tblp)
{
    int k = blockIdx.x * 64 + threadIdx.x;
    if (k < TBL_N) {
        float x0 = -8.0f + (float)k       * (1.0f / 32.0f);
        float x1 = -8.0f + (float)(k + 1) * (1.0f / 32.0f);
        float g0 = 0.5f * x0 * (1.0f + erff(x0 * 0.7071067811865476f));
        float g1 = 0.5f * x1 * (1.0f + erff(x1 * 0.7071067811865476f));
        tblp[2 * k + 0] = g0 - fmaxf(x0, 0.0f);
        tblp[2 * k + 1] = g1 - fmaxf(x1, 0.0f);
    }
}

// K-split prep: grid = 3 m  x 16 rowgroups x 8 k-chunks = 384 blocks.
extern "C" __global__ __launch_bounds__(256)
void cgl_prep(const float* __restrict__ state, const float* __restrict__ action,
              const float* __restrict__ embed, const float* __restrict__ W1,
              const float* __restrict__ b1, float* __restrict__ ws)
{
    __shared__ float arow[4][64];
    const int m   = blockIdx.x >> 7;       // 0=cause, 1=effect, 2=ctx
    const int rg  = (blockIdx.x >> 3) & 15;
    const int kc  = blockIdx.x & 7;
    const int tid = threadIdx.x;

    {   // stage 4 rows x 64 k's (exactly 256 values)
        int r = tid >> 6, kk = tid & 63;
        int row = rg * 4 + r, k = kc * 64 + kk;
        arow[r][kk] = (m == 2) ? (state[row * DIM + k] + action[row * DIM + k])
                               : embed[row * DIM + k];
    }
    __syncthreads();

    const float* Wm = W1 + m * DIM * HH + kc * 64 * HH;
    const int c = tid * 4;
    float4 acc0 = {0,0,0,0}, acc1 = {0,0,0,0}, acc2 = {0,0,0,0}, acc3 = {0,0,0,0};
    #pragma unroll 4
    for (int kk = 0; kk < 64; ++kk) {
        const float4 w = *reinterpret_cast<const float4*>(Wm + kk * HH + c);
        float a0 = arow[0][kk], a1 = arow[1][kk], a2 = arow[2][kk], a3 = arow[3][kk];
        acc0.x = fmaf(a0, w.x, acc0.x); acc0.y = fmaf(a0, w.y, acc0.y);
        acc0.z = fmaf(a0, w.z, acc0.z); acc0.w = fmaf(a0, w.w, acc0.w);
        acc1.x = fmaf(a1, w.x, acc1.x); acc1.y = fmaf(a1, w.y, acc1.y);
        acc1.z = fmaf(a1, w.z, acc1.z); acc1.w = fmaf(a1, w.w, acc1.w);
        acc2.x = fmaf(a2, w.x, acc2.x); acc2.y = fmaf(a2, w.y, acc2.y);
        acc2.z = fmaf(a2, w.z, acc2.z); acc2.w = fmaf(a2, w.w, acc2.w);
        acc3.x = fmaf(a3, w.x, acc3.x); acc3.y = fmaf(a3, w.y, acc3.y);
        acc3.z = fmaf(a3, w.z, acc3.z); acc3.w = fmaf(a3, w.w, acc3.w);
    }

    float* ctx   = ws;
    float* cause = ws + NB * HH;
    float* effT  = ws + 2 * NB * HH;
    float4 accs[4] = {acc0, acc1, acc2, acc3};

    if (m == 2 && kc == 0) {   // add bias exactly once
        const float4 bv = *reinterpret_cast<const float4*>(b1 + c);
        #pragma unroll
        for (int r = 0; r < 4; ++r) {
            accs[r].x += bv.x; accs[r].y += bv.y;
            accs[r].z += bv.z; accs[r].w += bv.w;
        }
    }

    #pragma unroll
    for (int r = 0; r < 4; ++r) {
        const int row = rg * 4 + r;
        if (m == 1) {
            atomicAdd(&effT[(c + 0) * NV + row], accs[r].x);
            atomicAdd(&effT[(c + 1) * NV + row], accs[r].y);
            atomicAdd(&effT[(c + 2) * NV + row], accs[r].z);
            atomicAdd(&effT[(c + 3) * NV + row], accs[r].w);
        } else {
            float* base = ((m == 0) ? cause : ctx) + row * HH + c;
            atomicAdd(base + 0, accs[r].x);
            atomicAdd(base + 1, accs[r].y);
            atomicAdd(base + 2, accs[r].z);
            atomicAdd(base + 3, accs[r].w);
        }
    }
}

// 512 threads = 8 waves: wave = (b_local 0..3) x (h-half 0..1).
// GELU via LDS residual table: y = max(x,0) + lerp(tbl, x) — ZERO trans ops.
// All operands from LDS (no s_loads: lgkmcnt aliasing regressed R7).
extern "C" __global__ __launch_bounds__(512, 8)
void cgl_score(const float* __restrict__ ws, const float* __restrict__ W2,
               const float* __restrict__ b2, float* __restrict__ out)
{
    __shared__ float comb[2][32][64];   // 16 KB: cause+eff chunk, both halves
    __shared__ float ctx_s[4][HH];      // 16 KB
    __shared__ float w2s[HH];           //  4 KB
    __shared__ float2 tblp[TBL_N];      //  4.1 KB
    __shared__ float red[8][64];        //  2 KB

    const float* ctx   = ws;
    const float* cause = ws + NB * HH;
    const float* effT  = ws + 2 * NB * HH;
    const float* tbg   = ws + 3 * NB * HH;

    const int i    = blockIdx.x & 63;
    const int bg   = blockIdx.x >> 6;      // 0..15
    const int tid  = threadIdx.x;
    const int lane = tid & 63;
    const int wave = tid >> 6;
    const int bq   = wave & 3;             // local b
    const int hh   = wave >> 2;            // h half (0/1)

    for (int idx = tid; idx < 4 * HH; idx += 512) {
        int w = idx >> 10, h = idx & (HH - 1);
        ctx_s[w][h] = ctx[(bg * 4 + w) * HH + h];
    }
    for (int h = tid; h < HH; h += 512) w2s[h] = W2[h];
    for (int k = tid; k < TBL_N; k += 512)
        tblp[k] = make_float2(tbg[2 * k], tbg[2 * k + 1]);

    float acc = 0.0f;
    for (int c = 0; c < 16; ++c) {
        __syncthreads();   // covers initial fills on c==0
        // stage comb[q][dh][j] = cause[i][q*512+c*32+dh] + effT[h][j]
        for (int idx = tid; idx < 1024; idx += 512) {
            int q  = idx >> 9;
            int r  = idx & 511;
            int dh = r >> 4;
            int jv = r & 15;
            int h  = q * 512 + c * 32 + dh;
            float  cs = cause[i * HH + h];
            float4 e4 = reinterpret_cast<const float4*>(effT + h * NV)[jv];
            float4 o;
            o.x = cs + e4.x; o.y = cs + e4.y; o.z = cs + e4.z; o.w = cs + e4.w;
            reinterpret_cast<float4*>(&comb[q][dh][0])[jv] = o;
        }
        __syncthreads();
        #pragma unroll
        for (int dh = 0; dh < 32; ++dh) {
            const int h = hh * 512 + c * 32 + dh;
            float x  = ctx_s[bq][h] + comb[hh][dh][lane];
            float xm = fmaxf(x, 0.0f);
            float u  = fmaf(x, 32.0f, 256.0f);          // table coordinate
            u = fminf(fmaxf(u, 0.0f), 511.0f);          // clamp (exact tails)
            int   k = (int)u;
            float f = u - (float)k;
            float2 g = tblp[k];                          // one ds_read_b64
            float r  = fmaf(f, g.y - g.x, g.x);          // lerp residual
            float w  = w2s[h];
            acc = fmaf(xm, w, acc);
            acc = fmaf(r,  w, acc);
        }
    }

    red[wave][lane] = acc;
    __syncthreads();
    if (wave < 4) {
        float logit = red[wave][lane] + red[wave + 4][lane] + b2[0];
        float s = __builtin_amdgcn_rcpf(
            1.0f + __builtin_amdgcn_exp2f(-1.4426950408889634f * logit));
        atomicAdd(&out[i * 64 + lane], s * (1.0f / 64.0f));
    }
}

extern "C" void kernel_launch(void* const* d_in, const int* in_sizes, int n_in,
                              void* d_out, int out_size, void* d_ws, size_t ws_size,
                              hipStream_t stream) {
    const float* state  = (const float*)d_in[0];
    const float* action = (const float*)d_in[1];
    const float* embed  = (const float*)d_in[2];
    const float* b1     = (const float*)d_in[4];
    const float* W1     = (const float*)d_in[3];
    const float* W2     = (const float*)d_in[5];
    const float* b2     = (const float*)d_in[6];
    float* ws = (float*)d_ws;

    hipMemsetAsync(d_out, 0, out_size * sizeof(float), stream);
    hipMemsetAsync(d_ws, 0, 3 * NB * HH * sizeof(float), stream);
    cgl_table<<<9, 64, 0, stream>>>(ws + 3 * NB * HH);
    cgl_prep<<<384, 256, 0, stream>>>(state, action, embed, W1, b1, ws);
    cgl_score<<<64 * 16, 512, 0, stream>>>(ws, W2, b2, (float*)d_out);
}

// Round 12
// 203.643 us; speedup vs baseline: 1.0331x; 1.0331x over previous
//
#include <hip/hip_runtime.h>

#define DIM 512
#define HH  1024
#define NB  64
#define NV  64

typedef float v2f __attribute__((ext_vector_type(2)));
typedef float v4f __attribute__((ext_vector_type(4)));

// Packed fp32 (VOP3P, CDNA2+) — one issue slot, two fp32 lanes-elements.
static __device__ __forceinline__ v2f pk_add(v2f a, v2f b) {
    v2f d; asm("v_pk_add_f32 %0, %1, %2" : "=v"(d) : "v"(a), "v"(b)); return d;
}
static __device__ __forceinline__ v2f pk_mul(v2f a, v2f b) {
    v2f d; asm("v_pk_mul_f32 %0, %1, %2" : "=v"(d) : "v"(a), "v"(b)); return d;
}
static __device__ __forceinline__ v2f pk_fma(v2f a, v2f b, v2f c) {
    v2f d; asm("v_pk_fma_f32 %0, %1, %2, %3" : "=v"(d) : "v"(a), "v"(b), "v"(c)); return d;
}

// ws layout (floats):
//   ctx   [64][1024]     @ 0        ((state+action)@Wx + b1)
//   cause [64][1024]     @ 65536    (embed@Wc)
//   effQ4 [256][64][4]   @ 131072   (embed@We as quads: effQ4[h/4][j][h%4])

// K-split prep: grid = 3 m x 16 rowgroups x 8 k-chunks = 384 blocks.
extern "C" __global__ __launch_bounds__(256)
void cgl_prep(const float* __restrict__ state, const float* __restrict__ action,
              const float* __restrict__ embed, const float* __restrict__ W1,
              const float* __restrict__ b1, float* __restrict__ ws)
{
    __shared__ float arow[4][64];
    const int m   = blockIdx.x >> 7;       // 0=cause, 1=effect, 2=ctx
    const int rg  = (blockIdx.x >> 3) & 15;
    const int kc  = blockIdx.x & 7;
    const int tid = threadIdx.x;

    {   // stage 4 rows x 64 k's (exactly 256 values)
        int r = tid >> 6, kk = tid & 63;
        int row = rg * 4 + r, k = kc * 64 + kk;
        arow[r][kk] = (m == 2) ? (state[row * DIM + k] + action[row * DIM + k])
                               : embed[row * DIM + k];
    }
    __syncthreads();

    const float* Wm = W1 + m * DIM * HH + kc * 64 * HH;
    const int c = tid * 4;                 // 4 consecutive h per thread
    float4 acc0 = {0,0,0,0}, acc1 = {0,0,0,0}, acc2 = {0,0,0,0}, acc3 = {0,0,0,0};
    #pragma unroll 4
    for (int kk = 0; kk < 64; ++kk) {
        const float4 w = *reinterpret_cast<const float4*>(Wm + kk * HH + c);
        float a0 = arow[0][kk], a1 = arow[1][kk], a2 = arow[2][kk], a3 = arow[3][kk];
        acc0.x = fmaf(a0, w.x, acc0.x); acc0.y = fmaf(a0, w.y, acc0.y);
        acc0.z = fmaf(a0, w.z, acc0.z); acc0.w = fmaf(a0, w.w, acc0.w);
        acc1.x = fmaf(a1, w.x, acc1.x); acc1.y = fmaf(a1, w.y, acc1.y);
        acc1.z = fmaf(a1, w.z, acc1.z); acc1.w = fmaf(a1, w.w, acc1.w);
        acc2.x = fmaf(a2, w.x, acc2.x); acc2.y = fmaf(a2, w.y, acc2.y);
        acc2.z = fmaf(a2, w.z, acc2.z); acc2.w = fmaf(a2, w.w, acc2.w);
        acc3.x = fmaf(a3, w.x, acc3.x); acc3.y = fmaf(a3, w.y, acc3.y);
        acc3.z = fmaf(a3, w.z, acc3.z); acc3.w = fmaf(a3, w.w, acc3.w);
    }

    float* ctx   = ws;
    float* cause = ws + NB * HH;
    float* effQ  = ws + 2 * NB * HH;
    float4 accs[4] = {acc0, acc1, acc2, acc3};

    if (m == 2 && kc == 0) {   // add bias exactly once
        const float4 bv = *reinterpret_cast<const float4*>(b1 + c);
        #pragma unroll
        for (int r = 0; r < 4; ++r) {
            accs[r].x += bv.x; accs[r].y += bv.y;
            accs[r].z += bv.z; accs[r].w += bv.w;
        }
    }

    #pragma unroll
    for (int r = 0; r < 4; ++r) {
        const int row = rg * 4 + r;
        if (m == 1) {
            // effQ4[h4 = tid][row][0..3] — the quad is exactly accs[r]
            float* base = effQ + (tid * 64 + row) * 4;
            atomicAdd(base + 0, accs[r].x);
            atomicAdd(base + 1, accs[r].y);
            atomicAdd(base + 2, accs[r].z);
            atomicAdd(base + 3, accs[r].w);
        } else {
            float* base = ((m == 0) ? cause : ctx) + row * HH + c;
            atomicAdd(base + 0, accs[r].x);
            atomicAdd(base + 1, accs[r].y);
            atomicAdd(base + 2, accs[r].z);
            atomicAdd(base + 3, accs[r].w);
        }
    }
}

// 512 threads = 8 waves: wave = (b_local 0..3) x (h-half 0..1); lane = j.
// Quad-step: 4 h per lane per step. 3 ds_read_b128 + 8 pk + 4 exp + 16 scalar
// = 31 issue slots / 4 elements. All operands via LDS (no s_loads).
extern "C" __global__ __launch_bounds__(512, 8)
void cgl_score(const float* __restrict__ ws, const float* __restrict__ W2,
               const float* __restrict__ b2, float* __restrict__ out)
{
    __shared__ v4f pre4[4][256];    // 16 KB: ctx[b]+cause[i] as quads
    __shared__ v4f eff4[2][8][64];  // 16 KB: eff chunk, both halves
    __shared__ v4f w24[256];        //  4 KB
    __shared__ float red[8][64];    //  2 KB

    const v4f* ctx4g   = (const v4f*)ws;
    const v4f* cause4g = (const v4f*)(ws + NB * HH);
    const v4f* effQ4g  = (const v4f*)(ws + 2 * NB * HH);
    const v4f* W24g    = (const v4f*)W2;

    const int i    = blockIdx.x & 63;
    const int bg   = blockIdx.x >> 6;      // 0..15
    const int tid  = threadIdx.x;
    const int lane = tid & 63;
    const int wave = tid >> 6;
    const int bq   = wave & 3;             // local b
    const int hh   = wave >> 2;            // h half (0/1)

    for (int idx = tid; idx < 1024; idx += 512) {       // 4 b x 256 quads
        int w = idx >> 8, h4 = idx & 255;
        v4f c4 = ctx4g[(bg * 4 + w) * 256 + h4];
        v4f a4 = cause4g[i * 256 + h4];
        pre4[w][h4] = c4 + a4;
    }
    for (int h4 = tid; h4 < 256; h4 += 512) w24[h4] = W24g[h4];

    const float C1 = -0.0713548162f * 1.4426950408889634f;
    const float C0 = -1.5957691216f * 1.4426950408889634f;
    const v2f C1p = {C1, C1};
    const v2f C0p = {C0, C0};

    float accA = 0.0f, accB = 0.0f, accC = 0.0f, accD = 0.0f;
    for (int c = 0; c < 16; ++c) {
        __syncthreads();   // covers initial fills on c==0
        for (int t = tid; t < 1024; t += 512) {          // pure copy, 16 KB
            int q = t >> 9, rem = t & 511, dq = rem >> 6, j = rem & 63;
            eff4[q][dq][j] = effQ4g[(q * 128 + c * 8 + dq) * 64 + j];
        }
        __syncthreads();
        const int hq = hh * 128 + c * 8;
        #pragma unroll
        for (int dq = 0; dq < 8; ++dq) {
            v4f e4 = eff4[hh][dq][lane];                 // ds_read_b128
            v4f p4 = pre4[bq][hq + dq];                  // broadcast b128
            v4f w4 = w24[hq + dq];                       // broadcast b128
            v2f e01 = __builtin_shufflevector(e4, e4, 0, 1);
            v2f e23 = __builtin_shufflevector(e4, e4, 2, 3);
            v2f p01 = __builtin_shufflevector(p4, p4, 0, 1);
            v2f p23 = __builtin_shufflevector(p4, p4, 2, 3);
            v2f x01 = pk_add(p01, e01);
            v2f x23 = pk_add(p23, e23);
            v2f s01 = pk_mul(x01, x01);
            v2f s23 = pk_mul(x23, x23);
            v2f t01 = pk_fma(s01, C1p, C0p);
            v2f t23 = pk_fma(s23, C1p, C0p);
            v2f u01 = pk_mul(x01, t01);
            v2f u23 = pk_mul(x23, t23);
            float ea = __builtin_amdgcn_exp2f(u01.x);
            float eb = __builtin_amdgcn_exp2f(u01.y);
            float ec = __builtin_amdgcn_exp2f(u23.x);
            float ed = __builtin_amdgcn_exp2f(u23.y);
            float ra = __builtin_amdgcn_rcpf(1.0f + ea);
            float rb = __builtin_amdgcn_rcpf(1.0f + eb);
            float rc = __builtin_amdgcn_rcpf(1.0f + ec);
            float rd = __builtin_amdgcn_rcpf(1.0f + ed);
            accA = fmaf(x01.x * ra, w4.x, accA);
            accB = fmaf(x01.y * rb, w4.y, accB);
            accC = fmaf(x23.x * rc, w4.z, accC);
            accD = fmaf(x23.y * rd, w4.w, accD);
        }
    }

    red[wave][lane] = (accA + accB) + (accC + accD);
    __syncthreads();
    if (wave < 4) {
        float logit = red[wave][lane] + red[wave + 4][lane] + b2[0];
        float s = __builtin_amdgcn_rcpf(
            1.0f + __builtin_amdgcn_exp2f(-1.4426950408889634f * logit));
        atomicAdd(&out[i * 64 + lane], s * (1.0f / 64.0f));
    }
}

extern "C" void kernel_launch(void* const* d_in, const int* in_sizes, int n_in,
                              void* d_out, int out_size, void* d_ws, size_t ws_size,
                              hipStream_t stream) {
    const float* state  = (const float*)d_in[0];
    const float* action = (const float*)d_in[1];
    const float* embed  = (const float*)d_in[2];
    const float* W1     = (const float*)d_in[3];
    const float* b1     = (const float*)d_in[4];
    const float* W2     = (const float*)d_in[5];
    const float* b2     = (const float*)d_in[6];
    float* ws = (float*)d_ws;

    hipMemsetAsync(d_out, 0, out_size * sizeof(float), stream);
    hipMemsetAsync(d_ws, 0, 3 * NB * HH * sizeof(float), stream);
    cgl_prep<<<384, 256, 0, stream>>>(state, action, embed, W1, b1, ws);
    cgl_score<<<64 * 16, 512, 0, stream>>>(ws, W2, b2, (float*)d_out);
}